// Round 1
// baseline (410.892 us; speedup 1.0000x reference)
//
#include <hip/hip_runtime.h>
#include <stdint.h>
#include <stddef.h>

// All-bf16 MFMA pipeline for MHSA: cvt -> gemm_qkv -> flash attn -> gemm_out.
// LDS tiles use XOR-swizzle on 16B granules so global_load_lds staging is
// coalesced AND ds_read_b128 frag reads are ~2-way conflict (free, m136).

typedef __attribute__((ext_vector_type(8))) short short8;   // bf16x8 frag (4 VGPRs)
typedef __attribute__((ext_vector_type(4))) float floatx4;  // C/D frag

#define MFMA_BF16(a, b, c) __builtin_amdgcn_mfma_f32_16x16x32_bf16((a), (b), (c), 0, 0, 0)

__device__ __forceinline__ unsigned short f32_bf16(float f) {
  union { float f; unsigned u; } v; v.f = f;
  unsigned r = v.u + 0x7fffu + ((v.u >> 16) & 1u);   // RNE
  return (unsigned short)(r >> 16);
}

__device__ __forceinline__ void g2l16(const void* g, void* l) {
  __builtin_amdgcn_global_load_lds((const __attribute__((address_space(1))) void*)g,
                                   (__attribute__((address_space(3))) void*)l,
                                   16, 0, 0);
}

// ---------------- conversion kernels ----------------

__global__ __launch_bounds__(256) void cvt_x_k(const float* __restrict__ x,
                                               unsigned short* __restrict__ xb) {
  int i = (blockIdx.x * 256 + threadIdx.x) * 4;
  float4 v = *(const float4*)(x + i);
  ushort4 o;
  o.x = f32_bf16(v.x); o.y = f32_bf16(v.y); o.z = f32_bf16(v.z); o.w = f32_bf16(v.w);
  *(ushort4*)(xb + i) = o;
}

// Wt[n][d] (n = typ*1024 + h*64 + dk), transposed so GEMM B-frags read rows.
__global__ __launch_bounds__(256) void cvt_wqkv_k(const float* __restrict__ WQ,
                                                  const float* __restrict__ WK,
                                                  const float* __restrict__ WV,
                                                  unsigned short* __restrict__ Wt) {
  int idx = blockIdx.x * 256 + threadIdx.x;     // n*1024 + d
  int n = idx >> 10, d = idx & 1023;
  int typ = n >> 10, rem = n & 1023;
  int h = rem >> 6, dk = rem & 63;
  const float* W = (typ == 0) ? WQ : ((typ == 1) ? WK : WV);
  Wt[idx] = f32_bf16(W[((size_t)h * 1024 + d) * 64 + dk]);
}

// WOt[n][k] = WO[k][n]
__global__ __launch_bounds__(256) void cvt_wo_k(const float* __restrict__ WO,
                                                unsigned short* __restrict__ Wt) {
  int idx = blockIdx.x * 256 + threadIdx.x;     // n*1024 + k
  int n = idx >> 10, k = idx & 1023;
  Wt[idx] = f32_bf16(WO[(size_t)k * 1024 + n]);
}

// ---------------- QKV projection GEMM ----------------
// A[8192][1024] bf16, Bt[3072][1024] bf16 (B^T). 128x128 tile, BK=64,
// 4 waves each 64x64 (4x4 16x16x32 MFMA tiles). Epilogue scatters to
// Q[bh][s][dk], K[bh][s][dk], V^T[bh][dk][s] (bf16).

__global__ __launch_bounds__(256, 2)
void gemm_qkv_k(const unsigned short* __restrict__ A,
                const unsigned short* __restrict__ Bt,
                unsigned short* __restrict__ Qo,
                unsigned short* __restrict__ Ko,
                unsigned short* __restrict__ Vo) {
  __shared__ __align__(16) unsigned short As[8192];
  __shared__ __align__(16) unsigned short Bs[8192];
  const int lane = threadIdx.x & 63;
  const int wave = threadIdx.x >> 6;
  const int quad = lane >> 4;
  const int t = lane & 15;
  const int wm = wave >> 1, wn = wave & 1;
  const int row0 = blockIdx.y * 128;
  const int col0 = blockIdx.x * 128;

  floatx4 acc[4][4];
  #pragma unroll
  for (int i = 0; i < 4; ++i)
    #pragma unroll
    for (int j = 0; j < 4; ++j) acc[i][j] = (floatx4)0.0f;

  for (int k0 = 0; k0 < 1024; k0 += 64) {
    #pragma unroll
    for (int i = 0; i < 4; ++i) {
      int s = (wave * 4 + i) * 64 + lane;       // 16B slot index
      int r = s >> 3, kc = (s & 7) ^ (r & 7);   // swizzle8
      g2l16(A  + (size_t)(row0 + r) * 1024 + k0 + kc * 8, As + (wave * 4 + i) * 512);
      g2l16(Bt + (size_t)(col0 + r) * 1024 + k0 + kc * 8, Bs + (wave * 4 + i) * 512);
    }
    __syncthreads();
    #pragma unroll
    for (int kk = 0; kk < 2; ++kk) {
      short8 af[4], bf[4];
      #pragma unroll
      for (int mt = 0; mt < 4; ++mt) {
        int r = wm * 64 + mt * 16 + t;
        int kc = (kk * 4 + quad) ^ (r & 7);
        af[mt] = *(const short8*)(As + (r * 8 + kc) * 8);
      }
      #pragma unroll
      for (int nt = 0; nt < 4; ++nt) {
        int r = wn * 64 + nt * 16 + t;
        int kc = (kk * 4 + quad) ^ (r & 7);
        bf[nt] = *(const short8*)(Bs + (r * 8 + kc) * 8);
      }
      #pragma unroll
      for (int mt = 0; mt < 4; ++mt)
        #pragma unroll
        for (int nt = 0; nt < 4; ++nt)
          acc[mt][nt] = MFMA_BF16(af[mt], bf[nt], acc[mt][nt]);
    }
    __syncthreads();
  }

  const int typ = col0 >> 10;  // block-uniform: 0=Q 1=K 2=V
  #pragma unroll
  for (int mt = 0; mt < 4; ++mt) {
    int grow0 = row0 + wm * 64 + mt * 16 + quad * 4;  // token, + rg
    int b = grow0 >> 11;
    int s = grow0 & 2047;
    #pragma unroll
    for (int nt = 0; nt < 4; ++nt) {
      int gcol = col0 + wn * 64 + nt * 16 + t;
      int rem = gcol & 1023;
      int h = rem >> 6, dk = rem & 63;
      int bh = b * 16 + h;
      if (typ == 0) {
        #pragma unroll
        for (int rg = 0; rg < 4; ++rg)
          Qo[((size_t)bh * 2048 + s + rg) * 64 + dk] = f32_bf16(acc[mt][nt][rg]);
      } else if (typ == 1) {
        #pragma unroll
        for (int rg = 0; rg < 4; ++rg)
          Ko[((size_t)bh * 2048 + s + rg) * 64 + dk] = f32_bf16(acc[mt][nt][rg]);
      } else {
        ushort4 pv;
        pv.x = f32_bf16(acc[mt][nt][0]);
        pv.y = f32_bf16(acc[mt][nt][1]);
        pv.z = f32_bf16(acc[mt][nt][2]);
        pv.w = f32_bf16(acc[mt][nt][3]);
        *(ushort4*)(Vo + ((size_t)bh * 64 + dk) * 2048 + s) = pv;  // V transposed
      }
    }
  }
}

// ---------------- flash attention ----------------
// One block = 64 query rows of one (b,h); 4 waves x 16 rows. Online softmax
// (exp2 domain, scale folded). P goes C/D-layout -> LDS (swizzled) -> A-frags.

__global__ __launch_bounds__(256, 2)
void attn_k(const unsigned short* __restrict__ Qg_,
            const unsigned short* __restrict__ Kg_,
            const unsigned short* __restrict__ Vg_,   // [bh][64][2048] (V^T)
            unsigned short* __restrict__ O) {         // [token][h*64+dk]
  __shared__ __align__(16) unsigned short Qs[4096];   // [64][64] swz8
  __shared__ __align__(16) unsigned short Ks[8192];   // [128][64] swz8
  __shared__ __align__(16) unsigned short Vs[8192];   // [64][128] swz16 (V^T tile)
  __shared__ __align__(16) unsigned short Ps[8192];   // 4 waves x [16][128] swz16
  const int lane = threadIdx.x & 63;
  const int wave = threadIdx.x >> 6;
  const int quad = lane >> 4;
  const int t = lane & 15;
  const int bh = blockIdx.y;
  const int q0 = blockIdx.x * 64;
  const unsigned short* Qg = Qg_ + ((size_t)bh * 2048 + q0) * 64;
  const unsigned short* Kg = Kg_ + (size_t)bh * 2048 * 64;
  const unsigned short* Vg = Vg_ + (size_t)bh * 64 * 2048;

  #pragma unroll
  for (int i = 0; i < 2; ++i) {
    int s = (wave * 2 + i) * 64 + lane;
    int r = s >> 3, kc = (s & 7) ^ (r & 7);
    g2l16(Qg + (size_t)r * 64 + kc * 8, Qs + (wave * 2 + i) * 512);
  }

  float m2[4], lsum[4];
  floatx4 acc[4];
  #pragma unroll
  for (int i = 0; i < 4; ++i) { m2[i] = -1e30f; lsum[i] = 0.0f; acc[i] = (floatx4)0.0f; }

  const float cs = 0.125f * 1.44269504088896340736f;  // scale * log2(e)

  for (int s0 = 0; s0 < 2048; s0 += 128) {
    #pragma unroll
    for (int i = 0; i < 4; ++i) {
      int s = (wave * 4 + i) * 64 + lane;
      int r = s >> 3, kc = (s & 7) ^ (r & 7);
      g2l16(Kg + (size_t)(s0 + r) * 64 + kc * 8, Ks + (wave * 4 + i) * 512);
    }
    #pragma unroll
    for (int i = 0; i < 4; ++i) {
      int s = (wave * 4 + i) * 64 + lane;
      int r = s >> 4, kc = (s & 15) ^ (r & 15);    // swizzle16
      g2l16(Vg + (size_t)r * 2048 + s0 + kc * 8, Vs + (wave * 4 + i) * 512);
    }
    __syncthreads();

    // S = Q K^T  (wave: 16 q-rows x 128 keys)
    floatx4 sc[8];
    #pragma unroll
    for (int nt = 0; nt < 8; ++nt) sc[nt] = (floatx4)0.0f;
    #pragma unroll
    for (int kk = 0; kk < 2; ++kk) {
      int rq = wave * 16 + t;
      int kcq = (kk * 4 + quad) ^ (rq & 7);
      short8 aq = *(const short8*)(Qs + (rq * 8 + kcq) * 8);
      #pragma unroll
      for (int nt = 0; nt < 8; ++nt) {
        int rk = nt * 16 + t;
        int kck = (kk * 4 + quad) ^ (rk & 7);
        short8 bk = *(const short8*)(Ks + (rk * 8 + kck) * 8);
        sc[nt] = MFMA_BF16(aq, bk, sc[nt]);
      }
    }

    // online softmax per row (row = quad*4+rg; 16 lanes/quad share a row)
    unsigned short* Pw = Ps + wave * 2048;
    #pragma unroll
    for (int rg = 0; rg < 4; ++rg) {
      float mx = sc[0][rg];
      #pragma unroll
      for (int nt = 1; nt < 8; ++nt) mx = fmaxf(mx, sc[nt][rg]);
      mx = fmaxf(mx, __shfl_xor(mx, 1));
      mx = fmaxf(mx, __shfl_xor(mx, 2));
      mx = fmaxf(mx, __shfl_xor(mx, 4));
      mx = fmaxf(mx, __shfl_xor(mx, 8));
      float mnew = fmaxf(m2[rg], mx * cs);
      float alpha = exp2f(m2[rg] - mnew);
      m2[rg] = mnew;
      float rs = 0.0f;
      int r = quad * 4 + rg;
      #pragma unroll
      for (int nt = 0; nt < 8; ++nt) {
        float p0 = exp2f(sc[nt][rg] * cs - mnew);
        rs += p0;
        int col = nt * 16 + t;
        int kc = (col >> 3) ^ (r & 15);
        Pw[(r * 16 + kc) * 8 + (col & 7)] = f32_bf16(p0);
      }
      rs += __shfl_xor(rs, 1);
      rs += __shfl_xor(rs, 2);
      rs += __shfl_xor(rs, 4);
      rs += __shfl_xor(rs, 8);
      lsum[rg] = lsum[rg] * alpha + rs;
      #pragma unroll
      for (int nt = 0; nt < 4; ++nt) acc[nt][rg] *= alpha;
    }

    // O += P V   (A = P from LDS, B = V^T tile)
    #pragma unroll
    for (int ks = 0; ks < 4; ++ks) {
      int rp = t;
      int kcp = (ks * 4 + quad) ^ (rp & 15);
      short8 ap = *(const short8*)(Pw + (rp * 16 + kcp) * 8);
      #pragma unroll
      for (int nt = 0; nt < 4; ++nt) {
        int rv = nt * 16 + t;
        int kcv = (ks * 4 + quad) ^ (rv & 15);
        short8 bv = *(const short8*)(Vs + (rv * 16 + kcv) * 8);
        acc[nt] = MFMA_BF16(ap, bv, acc[nt]);
      }
    }
    __syncthreads();
  }

  const int b = bh >> 4, h = bh & 15;
  #pragma unroll
  for (int rg = 0; rg < 4; ++rg) {
    float rl = 1.0f / lsum[rg];
    int token = b * 2048 + q0 + wave * 16 + quad * 4 + rg;
    #pragma unroll
    for (int nt = 0; nt < 4; ++nt) {
      int col = h * 64 + nt * 16 + t;
      O[(size_t)token * 1024 + col] = f32_bf16(acc[nt][rg] * rl);
    }
  }
}

// ---------------- output projection GEMM (fp32 out) ----------------

__global__ __launch_bounds__(256, 2)
void gemm_out_k(const unsigned short* __restrict__ A,    // O concat [8192][1024]
                const unsigned short* __restrict__ Bt,   // WOt [1024][1024]
                float* __restrict__ C) {
  __shared__ __align__(16) unsigned short As[8192];
  __shared__ __align__(16) unsigned short Bs[8192];
  const int lane = threadIdx.x & 63;
  const int wave = threadIdx.x >> 6;
  const int quad = lane >> 4;
  const int t = lane & 15;
  const int wm = wave >> 1, wn = wave & 1;
  const int row0 = blockIdx.y * 128;
  const int col0 = blockIdx.x * 128;

  floatx4 acc[4][4];
  #pragma unroll
  for (int i = 0; i < 4; ++i)
    #pragma unroll
    for (int j = 0; j < 4; ++j) acc[i][j] = (floatx4)0.0f;

  for (int k0 = 0; k0 < 1024; k0 += 64) {
    #pragma unroll
    for (int i = 0; i < 4; ++i) {
      int s = (wave * 4 + i) * 64 + lane;
      int r = s >> 3, kc = (s & 7) ^ (r & 7);
      g2l16(A  + (size_t)(row0 + r) * 1024 + k0 + kc * 8, As + (wave * 4 + i) * 512);
      g2l16(Bt + (size_t)(col0 + r) * 1024 + k0 + kc * 8, Bs + (wave * 4 + i) * 512);
    }
    __syncthreads();
    #pragma unroll
    for (int kk = 0; kk < 2; ++kk) {
      short8 af[4], bf[4];
      #pragma unroll
      for (int mt = 0; mt < 4; ++mt) {
        int r = wm * 64 + mt * 16 + t;
        int kc = (kk * 4 + quad) ^ (r & 7);
        af[mt] = *(const short8*)(As + (r * 8 + kc) * 8);
      }
      #pragma unroll
      for (int nt = 0; nt < 4; ++nt) {
        int r = wn * 64 + nt * 16 + t;
        int kc = (kk * 4 + quad) ^ (r & 7);
        bf[nt] = *(const short8*)(Bs + (r * 8 + kc) * 8);
      }
      #pragma unroll
      for (int mt = 0; mt < 4; ++mt)
        #pragma unroll
        for (int nt = 0; nt < 4; ++nt)
          acc[mt][nt] = MFMA_BF16(af[mt], bf[nt], acc[mt][nt]);
    }
    __syncthreads();
  }

  #pragma unroll
  for (int mt = 0; mt < 4; ++mt) {
    int grow0 = row0 + wm * 64 + mt * 16 + quad * 4;
    #pragma unroll
    for (int nt = 0; nt < 4; ++nt) {
      int gcol = col0 + wn * 64 + nt * 16 + t;
      #pragma unroll
      for (int rg = 0; rg < 4; ++rg)
        C[(size_t)(grow0 + rg) * 1024 + gcol] = acc[mt][nt][rg];
    }
  }
}

// ---------------- launcher ----------------

extern "C" void kernel_launch(void* const* d_in, const int* in_sizes, int n_in,
                              void* d_out, int out_size, void* d_ws, size_t ws_size,
                              hipStream_t stream) {
  const float* x  = (const float*)d_in[0];
  const float* WQ = (const float*)d_in[1];
  const float* WK = (const float*)d_in[2];
  const float* WV = (const float*)d_in[3];
  const float* WO = (const float*)d_in[4];
  char* ws = (char*)d_ws;
  // workspace layout (72 MB total):
  unsigned short* xb   = (unsigned short*)(ws);                              // 16MB; reused as O after gemm_qkv
  unsigned short* Wqkv = (unsigned short*)(ws + (size_t)16 * 1024 * 1024);   // 6MB  [3072][1024]
  unsigned short* WOt  = (unsigned short*)(ws + (size_t)22 * 1024 * 1024);   // 2MB  [1024][1024]
  unsigned short* Qb   = (unsigned short*)(ws + (size_t)24 * 1024 * 1024);   // 16MB [64][2048][64]
  unsigned short* Kb   = (unsigned short*)(ws + (size_t)40 * 1024 * 1024);   // 16MB [64][2048][64]
  unsigned short* Vb   = (unsigned short*)(ws + (size_t)56 * 1024 * 1024);   // 16MB [64][64][2048] (V^T)
  float* out = (float*)d_out;

  cvt_x_k<<<8192, 256, 0, stream>>>(x, xb);
  cvt_wqkv_k<<<12288, 256, 0, stream>>>(WQ, WK, WV, Wqkv);
  cvt_wo_k<<<4096, 256, 0, stream>>>(WO, WOt);
  gemm_qkv_k<<<dim3(24, 64), 256, 0, stream>>>(xb, Wqkv, Qb, Kb, Vb);
  attn_k<<<dim3(32, 64), 256, 0, stream>>>(Qb, Kb, Vb, xb /*O reuse*/);
  gemm_out_k<<<dim3(8, 64), 256, 0, stream>>>(xb, WOt, out);
}

// Round 3
// 281.805 us; speedup vs baseline: 1.4581x; 1.4581x over previous
//
#include <hip/hip_runtime.h>
#include <stdint.h>
#include <stddef.h>

// All-bf16 MFMA pipeline for MHSA: cvt -> gemm_qkv -> flash attn -> gemm_out.
// Attention v3: S^T = K*Q^T via 32x32x16 MFMA, fixed-base softmax (scale folded
// into Q at gemm_qkv epilogue), P converted C-layout -> A-layout IN REGISTERS
// (pack + shfl_xor(32) + cndmask) -- no P LDS round-trip, no hand waitcnt.

typedef __attribute__((ext_vector_type(8))) short short8;     // bf16x8 frag (4 VGPRs)
typedef __attribute__((ext_vector_type(4))) float floatx4;    // 16x16 C/D frag
typedef __attribute__((ext_vector_type(16))) float floatx16;  // 32x32 C/D frag

#define MFMA_BF16(a, b, c) __builtin_amdgcn_mfma_f32_16x16x32_bf16((a), (b), (c), 0, 0, 0)
#define MFMA32_BF16(a, b, c) __builtin_amdgcn_mfma_f32_32x32x16_bf16((a), (b), (c), 0, 0, 0)

__device__ __forceinline__ unsigned short f32_bf16(float f) {
  union { float f; unsigned u; } v; v.f = f;
  unsigned r = v.u + 0x7fffu + ((v.u >> 16) & 1u);   // RNE
  return (unsigned short)(r >> 16);
}

// pack two floats to bf16x2 (round-half-up): low=a, high=b
__device__ __forceinline__ unsigned pack_bf16_rh(float a, float b) {
  unsigned ua = __float_as_uint(a) + 0x8000u;
  unsigned ub = __float_as_uint(b) + 0x8000u;
  return __builtin_amdgcn_perm(ub, ua, 0x07060302u);
}

__device__ __forceinline__ float fast_exp2(float x) {
#if __has_builtin(__builtin_amdgcn_exp2f)
  return __builtin_amdgcn_exp2f(x);
#else
  return exp2f(x);
#endif
}

__device__ __forceinline__ void g2l16(const void* g, void* l) {
  __builtin_amdgcn_global_load_lds((const __attribute__((address_space(1))) void*)g,
                                   (__attribute__((address_space(3))) void*)l,
                                   16, 0, 0);
}

// ---------------- conversion kernels ----------------

__global__ __launch_bounds__(256) void cvt_x_k(const float* __restrict__ x,
                                               unsigned short* __restrict__ xb) {
  int i = (blockIdx.x * 256 + threadIdx.x) * 4;
  float4 v = *(const float4*)(x + i);
  ushort4 o;
  o.x = f32_bf16(v.x); o.y = f32_bf16(v.y); o.z = f32_bf16(v.z); o.w = f32_bf16(v.w);
  *(ushort4*)(xb + i) = o;
}

// Wt[n][d] (n = typ*1024 + h*64 + dk), transposed so GEMM B-frags read rows.
__global__ __launch_bounds__(256) void cvt_wqkv_k(const float* __restrict__ WQ,
                                                  const float* __restrict__ WK,
                                                  const float* __restrict__ WV,
                                                  unsigned short* __restrict__ Wt) {
  int idx = blockIdx.x * 256 + threadIdx.x;     // n*1024 + d
  int n = idx >> 10, d = idx & 1023;
  int typ = n >> 10, rem = n & 1023;
  int h = rem >> 6, dk = rem & 63;
  const float* W = (typ == 0) ? WQ : ((typ == 1) ? WK : WV);
  Wt[idx] = f32_bf16(W[((size_t)h * 1024 + d) * 64 + dk]);
}

// WOt[n][k] = WO[k][n]
__global__ __launch_bounds__(256) void cvt_wo_k(const float* __restrict__ WO,
                                                unsigned short* __restrict__ Wt) {
  int idx = blockIdx.x * 256 + threadIdx.x;     // n*1024 + k
  int n = idx >> 10, k = idx & 1023;
  Wt[idx] = f32_bf16(WO[(size_t)k * 1024 + n]);
}

// ---------------- QKV projection GEMM ----------------
// A[8192][1024] bf16, Bt[3072][1024] bf16 (B^T). 128x128 tile, BK=64,
// 4 waves each 64x64 (4x4 16x16x32 MFMA tiles). Epilogue scatters to
// Q (pre-scaled by 0.125*log2e), K [bh][s][dk], V^T [bh][dk][s] (bf16).

__global__ __launch_bounds__(256, 2)
void gemm_qkv_k(const unsigned short* __restrict__ A,
                const unsigned short* __restrict__ Bt,
                unsigned short* __restrict__ Qo,
                unsigned short* __restrict__ Ko,
                unsigned short* __restrict__ Vo) {
  __shared__ __align__(16) unsigned short As[8192];
  __shared__ __align__(16) unsigned short Bs[8192];
  const int lane = threadIdx.x & 63;
  const int wave = threadIdx.x >> 6;
  const int quad = lane >> 4;
  const int t = lane & 15;
  const int wm = wave >> 1, wn = wave & 1;
  const int row0 = blockIdx.y * 128;
  const int col0 = blockIdx.x * 128;

  floatx4 acc[4][4];
  #pragma unroll
  for (int i = 0; i < 4; ++i)
    #pragma unroll
    for (int j = 0; j < 4; ++j) acc[i][j] = (floatx4)0.0f;

  for (int k0 = 0; k0 < 1024; k0 += 64) {
    #pragma unroll
    for (int i = 0; i < 4; ++i) {
      int s = (wave * 4 + i) * 64 + lane;       // 16B slot index
      int r = s >> 3, kc = (s & 7) ^ (r & 7);   // swizzle8
      g2l16(A  + (size_t)(row0 + r) * 1024 + k0 + kc * 8, As + (wave * 4 + i) * 512);
      g2l16(Bt + (size_t)(col0 + r) * 1024 + k0 + kc * 8, Bs + (wave * 4 + i) * 512);
    }
    __syncthreads();
    #pragma unroll
    for (int kk = 0; kk < 2; ++kk) {
      short8 af[4], bf[4];
      #pragma unroll
      for (int mt = 0; mt < 4; ++mt) {
        int r = wm * 64 + mt * 16 + t;
        int kc = (kk * 4 + quad) ^ (r & 7);
        af[mt] = *(const short8*)(As + (r * 8 + kc) * 8);
      }
      #pragma unroll
      for (int nt = 0; nt < 4; ++nt) {
        int r = wn * 64 + nt * 16 + t;
        int kc = (kk * 4 + quad) ^ (r & 7);
        bf[nt] = *(const short8*)(Bs + (r * 8 + kc) * 8);
      }
      #pragma unroll
      for (int mt = 0; mt < 4; ++mt)
        #pragma unroll
        for (int nt = 0; nt < 4; ++nt)
          acc[mt][nt] = MFMA_BF16(af[mt], bf[nt], acc[mt][nt]);
    }
    __syncthreads();
  }

  const int typ = col0 >> 10;  // block-uniform: 0=Q 1=K 2=V
  const float qscale = 0.18033688011112042f;  // 0.125 * log2(e) folded into Q
  #pragma unroll
  for (int mt = 0; mt < 4; ++mt) {
    int grow0 = row0 + wm * 64 + mt * 16 + quad * 4;  // token, + rg
    int b = grow0 >> 11;
    int s = grow0 & 2047;
    #pragma unroll
    for (int nt = 0; nt < 4; ++nt) {
      int gcol = col0 + wn * 64 + nt * 16 + t;
      int rem = gcol & 1023;
      int h = rem >> 6, dk = rem & 63;
      int bhh = b * 16 + h;
      if (typ == 0) {
        #pragma unroll
        for (int rg = 0; rg < 4; ++rg)
          Qo[((size_t)bhh * 2048 + s + rg) * 64 + dk] = f32_bf16(acc[mt][nt][rg] * qscale);
      } else if (typ == 1) {
        #pragma unroll
        for (int rg = 0; rg < 4; ++rg)
          Ko[((size_t)bhh * 2048 + s + rg) * 64 + dk] = f32_bf16(acc[mt][nt][rg]);
      } else {
        ushort4 pv;
        pv.x = f32_bf16(acc[mt][nt][0]);
        pv.y = f32_bf16(acc[mt][nt][1]);
        pv.z = f32_bf16(acc[mt][nt][2]);
        pv.w = f32_bf16(acc[mt][nt][3]);
        *(ushort4*)(Vo + ((size_t)bhh * 64 + dk) * 2048 + s) = pv;  // V transposed
      }
    }
  }
}

// ---------------- flash attention v3 ----------------
// Block = 128 q rows of one (b,h); 4 waves x 32 rows; 32x32x16 MFMA.
// S^T = K*Q^T (C-layout: lane holds scores of query c32, keys split by h32).
// p = exp2(s) fixed-base (Q pre-scaled). P goes to PV A-operand layout via
// register packing + shfl_xor(32) + cndmask -- NO LDS round-trip.
// LDS: K 8K + V 8K + Q 16K = 32KB.

__global__ __launch_bounds__(256, 3)
void attn_k(const unsigned short* __restrict__ Qg_,  // [bh][2048][64], pre-scaled
            const unsigned short* __restrict__ Kg_,  // [bh][2048][64]
            const unsigned short* __restrict__ Vg_,  // [bh][64][2048] (V^T)
            unsigned short* __restrict__ O) {        // [token][h*64+dk]
  __shared__ __align__(16) char smem[32768];         // K@0, V@8192, Q@16384
  const int lane = threadIdx.x & 63;
  const int wave = threadIdx.x >> 6;
  const int h32 = lane >> 5;
  const int c32 = lane & 31;
  const int bh = blockIdx.y;
  const int q0 = blockIdx.x * 128;
  const unsigned short* Qg = Qg_ + ((size_t)bh * 2048 + q0) * 64;
  const unsigned short* Kg = Kg_ + (size_t)bh * 2048 * 64;
  const unsigned short* Vg = Vg_ + (size_t)bh * 64 * 2048;

  // stage Q (128x64 bf16 = 16KB) swz8 at smem+16384
  #pragma unroll
  for (int i = 0; i < 4; ++i) {
    int s = (wave * 4 + i) * 64 + lane;
    int r = s >> 3, kc = (s & 7) ^ (r & 7);
    g2l16(Qg + (size_t)r * 64 + kc * 8, smem + 16384 + (wave * 4 + i) * 1024);
  }
  __syncthreads();

  short8 qf[4];  // B-operand: Q rows (n = c32), d-chunks
  {
    int rq = wave * 32 + c32;
    #pragma unroll
    for (int dc = 0; dc < 4; ++dc) {
      int kc = (dc * 2 + h32) ^ (c32 & 7);
      qf[dc] = *(const short8*)(smem + 16384 + (rq * 8 + kc) * 16);
    }
  }

  floatx16 acc[2];
  acc[0] = (floatx16)0.0f; acc[1] = (floatx16)0.0f;
  float rsp = 0.0f;   // per-lane partial row sum (this lane's h32-half of keys)

  for (int s0 = 0; s0 < 2048; s0 += 64) {
    // stage K [64][64] swz8 @0, V^T [64][64] swz8 @8192
    #pragma unroll
    for (int i = 0; i < 2; ++i) {
      int s = (wave * 2 + i) * 64 + lane;
      int r = s >> 3, kc = (s & 7) ^ (r & 7);
      g2l16(Kg + (size_t)(s0 + r) * 64 + kc * 8, smem + (wave * 2 + i) * 1024);
      g2l16(Vg + (size_t)r * 2048 + s0 + kc * 8, smem + 8192 + (wave * 2 + i) * 1024);
    }
    __syncthreads();

    #pragma unroll
    for (int kb = 0; kb < 2; ++kb) {
      // S^T = K * Q^T for 32 keys (kb block)
      floatx16 sc = (floatx16)0.0f;
      #pragma unroll
      for (int dc = 0; dc < 4; ++dc) {
        int rk = kb * 32 + c32;
        int kc = (dc * 2 + h32) ^ (c32 & 7);
        short8 kf = *(const short8*)(smem + (rk * 8 + kc) * 16);
        sc = MFMA32_BF16(kf, qf[dc], sc);
      }
      // p = exp2(s); reg r holds key (r&3) + 8*(r>>2) + 4*h32 of this kb block
      float p[16];
      #pragma unroll
      for (int r = 0; r < 16; ++r) { p[r] = fast_exp2(sc[r]); rsp += p[r]; }
      // pack pairs: pk[i] = bf16x2(p[2i], p[2i+1])
      unsigned pk[8];
      #pragma unroll
      for (int i = 0; i < 8; ++i) pk[i] = pack_bf16_rh(p[2 * i], p[2 * i + 1]);
      // exchange with h32 partner: one shfl carries different packs each way
      unsigned x0 = __shfl_xor((int)(h32 ? pk[0] : pk[2]), 32);  // h32=0 gets pp0, h32=1 gets pp2
      unsigned x1 = __shfl_xor((int)(h32 ? pk[1] : pk[3]), 32);  // pp1 / pp3
      unsigned x2 = __shfl_xor((int)(h32 ? pk[4] : pk[6]), 32);  // pp4 / pp6
      unsigned x3 = __shfl_xor((int)(h32 ? pk[5] : pk[7]), 32);  // pp5 / pp7
      // assemble PV A-frags (m = query c32, k-chunk = 8*h32 + j) for the two
      // 16-key steps of this kb block
      union { unsigned u[4]; short8 s8; } af0, af1;
      af0.u[0] = h32 ? x0 : pk[0];  af0.u[1] = h32 ? x1 : pk[1];
      af0.u[2] = h32 ? pk[2] : x0;  af0.u[3] = h32 ? pk[3] : x1;
      af1.u[0] = h32 ? x2 : pk[4];  af1.u[1] = h32 ? x3 : pk[5];
      af1.u[2] = h32 ? pk[6] : x2;  af1.u[3] = h32 ? pk[7] : x3;
      // O += P * V (B = V^T rows: n = dk)
      #pragma unroll
      for (int ksp = 0; ksp < 2; ++ksp) {
        short8 af = ksp ? af1.s8 : af0.s8;
        int cc = kb * 4 + ksp * 2 + h32;        // 8-key chunk within 64-tile
        #pragma unroll
        for (int nb = 0; nb < 2; ++nb) {
          int rv = nb * 32 + c32;
          int kcv = cc ^ (c32 & 7);
          short8 bv = *(const short8*)(smem + 8192 + (rv * 8 + kcv) * 16);
          acc[nb] = MFMA32_BF16(af, bv, acc[nb]);
        }
      }
    }
    __syncthreads();
  }

  float lsum = rsp + __shfl_xor(rsp, 32);  // full row sum for query c32 (both halves)

  const int b = bh >> 4, h = bh & 15;
  #pragma unroll
  for (int g = 0; g < 4; ++g) {
    #pragma unroll
    for (int rr = 0; rr < 4; ++rr) {
      int qrel = rr + 8 * g + 4 * h32;          // 32x32 C/D row mapping
      float rl = 1.0f / __shfl(lsum, qrel);     // lane qrel holds row sum of query qrel
      int token = b * 2048 + q0 + wave * 32 + qrel;
      size_t base = (size_t)token * 1024 + h * 64;
      O[base + c32]      = f32_bf16(acc[0][4 * g + rr] * rl);
      O[base + 32 + c32] = f32_bf16(acc[1][4 * g + rr] * rl);
    }
  }
}

// ---------------- output projection GEMM (fp32 out) ----------------

__global__ __launch_bounds__(256, 2)
void gemm_out_k(const unsigned short* __restrict__ A,    // O concat [8192][1024]
                const unsigned short* __restrict__ Bt,   // WOt [1024][1024]
                float* __restrict__ C) {
  __shared__ __align__(16) unsigned short As[8192];
  __shared__ __align__(16) unsigned short Bs[8192];
  const int lane = threadIdx.x & 63;
  const int wave = threadIdx.x >> 6;
  const int quad = lane >> 4;
  const int t = lane & 15;
  const int wm = wave >> 1, wn = wave & 1;
  const int row0 = blockIdx.y * 128;
  const int col0 = blockIdx.x * 128;

  floatx4 acc[4][4];
  #pragma unroll
  for (int i = 0; i < 4; ++i)
    #pragma unroll
    for (int j = 0; j < 4; ++j) acc[i][j] = (floatx4)0.0f;

  for (int k0 = 0; k0 < 1024; k0 += 64) {
    #pragma unroll
    for (int i = 0; i < 4; ++i) {
      int s = (wave * 4 + i) * 64 + lane;
      int r = s >> 3, kc = (s & 7) ^ (r & 7);
      g2l16(A  + (size_t)(row0 + r) * 1024 + k0 + kc * 8, As + (wave * 4 + i) * 512);
      g2l16(Bt + (size_t)(col0 + r) * 1024 + k0 + kc * 8, Bs + (wave * 4 + i) * 512);
    }
    __syncthreads();
    #pragma unroll
    for (int kk = 0; kk < 2; ++kk) {
      short8 af[4], bf[4];
      #pragma unroll
      for (int mt = 0; mt < 4; ++mt) {
        int r = wm * 64 + mt * 16 + t;
        int kc = (kk * 4 + quad) ^ (r & 7);
        af[mt] = *(const short8*)(As + (r * 8 + kc) * 8);
      }
      #pragma unroll
      for (int nt = 0; nt < 4; ++nt) {
        int r = wn * 64 + nt * 16 + t;
        int kc = (kk * 4 + quad) ^ (r & 7);
        bf[nt] = *(const short8*)(Bs + (r * 8 + kc) * 8);
      }
      #pragma unroll
      for (int mt = 0; mt < 4; ++mt)
        #pragma unroll
        for (int nt = 0; nt < 4; ++nt)
          acc[mt][nt] = MFMA_BF16(af[mt], bf[nt], acc[mt][nt]);
    }
    __syncthreads();
  }

  #pragma unroll
  for (int mt = 0; mt < 4; ++mt) {
    int grow0 = row0 + wm * 64 + mt * 16 + quad * 4;
    #pragma unroll
    for (int nt = 0; nt < 4; ++nt) {
      int gcol = col0 + wn * 64 + nt * 16 + t;
      #pragma unroll
      for (int rg = 0; rg < 4; ++rg)
        C[(size_t)(grow0 + rg) * 1024 + gcol] = acc[mt][nt][rg];
    }
  }
}

// ---------------- launcher ----------------

extern "C" void kernel_launch(void* const* d_in, const int* in_sizes, int n_in,
                              void* d_out, int out_size, void* d_ws, size_t ws_size,
                              hipStream_t stream) {
  const float* x  = (const float*)d_in[0];
  const float* WQ = (const float*)d_in[1];
  const float* WK = (const float*)d_in[2];
  const float* WV = (const float*)d_in[3];
  const float* WO = (const float*)d_in[4];
  char* ws = (char*)d_ws;
  // workspace layout (72 MB total):
  unsigned short* xb   = (unsigned short*)(ws);                              // 16MB; reused as O after gemm_qkv
  unsigned short* Wqkv = (unsigned short*)(ws + (size_t)16 * 1024 * 1024);   // 6MB  [3072][1024]
  unsigned short* WOt  = (unsigned short*)(ws + (size_t)22 * 1024 * 1024);   // 2MB  [1024][1024]
  unsigned short* Qb   = (unsigned short*)(ws + (size_t)24 * 1024 * 1024);   // 16MB [64][2048][64]
  unsigned short* Kb   = (unsigned short*)(ws + (size_t)40 * 1024 * 1024);   // 16MB [64][2048][64]
  unsigned short* Vb   = (unsigned short*)(ws + (size_t)56 * 1024 * 1024);   // 16MB [64][64][2048] (V^T)
  float* out = (float*)d_out;

  cvt_x_k<<<8192, 256, 0, stream>>>(x, xb);
  cvt_wqkv_k<<<12288, 256, 0, stream>>>(WQ, WK, WV, Wqkv);
  cvt_wo_k<<<4096, 256, 0, stream>>>(WO, WOt);
  gemm_qkv_k<<<dim3(24, 64), 256, 0, stream>>>(xb, Wqkv, Qb, Kb, Vb);
  attn_k<<<dim3(16, 64), 256, 0, stream>>>(Qb, Kb, Vb, xb /*O reuse*/);
  gemm_out_k<<<dim3(8, 64), 256, 0, stream>>>(xb, WOt, out);
}

// Round 4
// 270.057 us; speedup vs baseline: 1.5215x; 1.0435x over previous
//
#include <hip/hip_runtime.h>
#include <stdint.h>
#include <stddef.h>

// All-bf16 MFMA pipeline for MHSA: cvt -> gemm_qkv -> flash attn -> gemm_out.
// Attention v4: S^T = K*Q^T via 32x32x16 MFMA, fixed-base softmax (scale folded
// into Q). PV uses a PERMUTED MFMA k-axis so each half-wave consumes only the
// P values it already holds (no cross-half exchange at all); V^T B-frags are
// assembled from two b64 LDS reads selecting the matching key sub-chunks.
// Q frags come straight from global (one-time). LDS 16KB (K+V only).

typedef __attribute__((ext_vector_type(8))) short short8;     // bf16x8 frag (4 VGPRs)
typedef __attribute__((ext_vector_type(4))) float floatx4;    // 16x16 C/D frag
typedef __attribute__((ext_vector_type(16))) float floatx16;  // 32x32 C/D frag

#define MFMA_BF16(a, b, c) __builtin_amdgcn_mfma_f32_16x16x32_bf16((a), (b), (c), 0, 0, 0)
#define MFMA32_BF16(a, b, c) __builtin_amdgcn_mfma_f32_32x32x16_bf16((a), (b), (c), 0, 0, 0)

__device__ __forceinline__ unsigned short f32_bf16(float f) {
  union { float f; unsigned u; } v; v.f = f;
  unsigned r = v.u + 0x7fffu + ((v.u >> 16) & 1u);   // RNE
  return (unsigned short)(r >> 16);
}

// pack two floats to bf16x2 (round-half-up): low=a, high=b
__device__ __forceinline__ unsigned pack_bf16_rh(float a, float b) {
  unsigned ua = __float_as_uint(a) + 0x8000u;
  unsigned ub = __float_as_uint(b) + 0x8000u;
  return __builtin_amdgcn_perm(ub, ua, 0x07060302u);
}

__device__ __forceinline__ float fast_exp2(float x) {
#if __has_builtin(__builtin_amdgcn_exp2f)
  return __builtin_amdgcn_exp2f(x);
#else
  return exp2f(x);
#endif
}

__device__ __forceinline__ void g2l16(const void* g, void* l) {
  __builtin_amdgcn_global_load_lds((const __attribute__((address_space(1))) void*)g,
                                   (__attribute__((address_space(3))) void*)l,
                                   16, 0, 0);
}

// ---------------- conversion kernels ----------------

__global__ __launch_bounds__(256) void cvt_x_k(const float* __restrict__ x,
                                               unsigned short* __restrict__ xb) {
  int i = (blockIdx.x * 256 + threadIdx.x) * 4;
  float4 v = *(const float4*)(x + i);
  ushort4 o;
  o.x = f32_bf16(v.x); o.y = f32_bf16(v.y); o.z = f32_bf16(v.z); o.w = f32_bf16(v.w);
  *(ushort4*)(xb + i) = o;
}

// LDS-tiled transpose-convert: Wt[typ*1024 + h*64 + dk][d] = W_typ[h][d][dk].
// grid (16 d-tiles, 48 = typ*16+h). Coalesced read (dk-major) + write (d-major).
__global__ __launch_bounds__(256) void cvt_wqkv_t(const float* __restrict__ WQ,
                                                  const float* __restrict__ WK,
                                                  const float* __restrict__ WV,
                                                  unsigned short* __restrict__ Wt) {
  __shared__ unsigned short tile[64][72];
  const int th = blockIdx.y;
  const int typ = th >> 4, h = th & 15;
  const float* W = (typ == 0) ? WQ : ((typ == 1) ? WK : WV);
  const float* src = W + ((size_t)h * 1024 + blockIdx.x * 64) * 64;  // [64 d][64 dk]
  const int tid = threadIdx.x;
  #pragma unroll
  for (int it = 0; it < 16; ++it) {
    int f = it * 256 + tid;
    int dk = f & 63, dl = f >> 6;
    tile[dk][dl] = f32_bf16(src[(size_t)dl * 64 + dk]);
  }
  __syncthreads();
  unsigned short* dst = Wt + (size_t)(typ * 1024 + h * 64) * 1024 + blockIdx.x * 64;
  #pragma unroll
  for (int it = 0; it < 16; ++it) {
    int f = it * 256 + tid;
    int d = f & 63, dk = f >> 6;
    dst[(size_t)dk * 1024 + d] = tile[dk][d];
  }
}

// LDS-tiled transpose-convert: WOt[n][k] = WO[k][n]. grid (16 n-tiles, 16 k-tiles).
__global__ __launch_bounds__(256) void cvt_wo_t(const float* __restrict__ WO,
                                                unsigned short* __restrict__ Wt) {
  __shared__ unsigned short tile[64][72];
  const int nt = blockIdx.x * 64, kt = blockIdx.y * 64;
  const int tid = threadIdx.x;
  #pragma unroll
  for (int it = 0; it < 16; ++it) {
    int f = it * 256 + tid;
    int n = f & 63, kl = f >> 6;
    tile[n][kl] = f32_bf16(WO[(size_t)(kt + kl) * 1024 + nt + n]);
  }
  __syncthreads();
  #pragma unroll
  for (int it = 0; it < 16; ++it) {
    int f = it * 256 + tid;
    int k = f & 63, nl = f >> 6;
    Wt[(size_t)(nt + nl) * 1024 + kt + k] = tile[nl][k];
  }
}

// ---------------- QKV projection GEMM ----------------
// A[8192][1024] bf16, Bt[3072][1024] bf16 (B^T). 128x128 tile, BK=64,
// 4 waves each 64x64 (4x4 16x16x32 MFMA tiles). Epilogue scatters to
// Q (pre-scaled by 0.125*log2e), K [bh][s][dk], V^T [bh][dk][s] (bf16).

__global__ __launch_bounds__(256, 2)
void gemm_qkv_k(const unsigned short* __restrict__ A,
                const unsigned short* __restrict__ Bt,
                unsigned short* __restrict__ Qo,
                unsigned short* __restrict__ Ko,
                unsigned short* __restrict__ Vo) {
  __shared__ __align__(16) unsigned short As[8192];
  __shared__ __align__(16) unsigned short Bs[8192];
  const int lane = threadIdx.x & 63;
  const int wave = threadIdx.x >> 6;
  const int quad = lane >> 4;
  const int t = lane & 15;
  const int wm = wave >> 1, wn = wave & 1;
  const int row0 = blockIdx.y * 128;
  const int col0 = blockIdx.x * 128;

  floatx4 acc[4][4];
  #pragma unroll
  for (int i = 0; i < 4; ++i)
    #pragma unroll
    for (int j = 0; j < 4; ++j) acc[i][j] = (floatx4)0.0f;

  for (int k0 = 0; k0 < 1024; k0 += 64) {
    #pragma unroll
    for (int i = 0; i < 4; ++i) {
      int s = (wave * 4 + i) * 64 + lane;       // 16B slot index
      int r = s >> 3, kc = (s & 7) ^ (r & 7);   // swizzle8
      g2l16(A  + (size_t)(row0 + r) * 1024 + k0 + kc * 8, As + (wave * 4 + i) * 512);
      g2l16(Bt + (size_t)(col0 + r) * 1024 + k0 + kc * 8, Bs + (wave * 4 + i) * 512);
    }
    __syncthreads();
    #pragma unroll
    for (int kk = 0; kk < 2; ++kk) {
      short8 af[4], bf[4];
      #pragma unroll
      for (int mt = 0; mt < 4; ++mt) {
        int r = wm * 64 + mt * 16 + t;
        int kc = (kk * 4 + quad) ^ (r & 7);
        af[mt] = *(const short8*)(As + (r * 8 + kc) * 8);
      }
      #pragma unroll
      for (int nt = 0; nt < 4; ++nt) {
        int r = wn * 64 + nt * 16 + t;
        int kc = (kk * 4 + quad) ^ (r & 7);
        bf[nt] = *(const short8*)(Bs + (r * 8 + kc) * 8);
      }
      #pragma unroll
      for (int mt = 0; mt < 4; ++mt)
        #pragma unroll
        for (int nt = 0; nt < 4; ++nt)
          acc[mt][nt] = MFMA_BF16(af[mt], bf[nt], acc[mt][nt]);
    }
    __syncthreads();
  }

  const int typ = col0 >> 10;  // block-uniform: 0=Q 1=K 2=V
  const float qscale = 0.18033688011112042f;  // 0.125 * log2(e) folded into Q
  #pragma unroll
  for (int mt = 0; mt < 4; ++mt) {
    int grow0 = row0 + wm * 64 + mt * 16 + quad * 4;  // token, + rg
    int b = grow0 >> 11;
    int s = grow0 & 2047;
    #pragma unroll
    for (int nt = 0; nt < 4; ++nt) {
      int gcol = col0 + wn * 64 + nt * 16 + t;
      int rem = gcol & 1023;
      int h = rem >> 6, dk = rem & 63;
      int bhh = b * 16 + h;
      if (typ == 0) {
        #pragma unroll
        for (int rg = 0; rg < 4; ++rg)
          Qo[((size_t)bhh * 2048 + s + rg) * 64 + dk] = f32_bf16(acc[mt][nt][rg] * qscale);
      } else if (typ == 1) {
        #pragma unroll
        for (int rg = 0; rg < 4; ++rg)
          Ko[((size_t)bhh * 2048 + s + rg) * 64 + dk] = f32_bf16(acc[mt][nt][rg]);
      } else {
        ushort4 pv;
        pv.x = f32_bf16(acc[mt][nt][0]);
        pv.y = f32_bf16(acc[mt][nt][1]);
        pv.z = f32_bf16(acc[mt][nt][2]);
        pv.w = f32_bf16(acc[mt][nt][3]);
        *(ushort4*)(Vo + ((size_t)bhh * 64 + dk) * 2048 + s) = pv;  // V transposed
      }
    }
  }
}

// ---------------- flash attention v4 ----------------
// Block = 128 q rows of one (b,h); 4 waves x 32 rows; 32x32x16 MFMA.
// S^T C-layout: lane (c32,h32) reg r holds P[key kb*32+(r&3)+8*(r>>2)+4*h32][query c32].
// PV k-axis permuted: step s covers keys {0-3,8-11}(h32=0) / {4-7,12-15}(h32=1)
// of sub-block base kb*32+s*16 -> A-frag = pk[0..3] / pk[4..7] verbatim;
// B-frag (V^T) = two b64 reads picking the matching 4-key chunks.

__global__ __launch_bounds__(256, 4)
void attn_k(const unsigned short* __restrict__ Qg_,  // [bh][2048][64], pre-scaled
            const unsigned short* __restrict__ Kg_,  // [bh][2048][64]
            const unsigned short* __restrict__ Vg_,  // [bh][64][2048] (V^T)
            unsigned short* __restrict__ O) {        // [token][h*64+dk]
  __shared__ __align__(16) char smem[16384];         // K@0, V@8192
  const int lane = threadIdx.x & 63;
  const int wave = threadIdx.x >> 6;
  const int h32 = lane >> 5;
  const int c32 = lane & 31;
  const int bh = blockIdx.y;
  const int q0 = blockIdx.x * 128;
  const unsigned short* Qg = Qg_ + ((size_t)bh * 2048 + q0) * 64;
  const unsigned short* Kg = Kg_ + (size_t)bh * 2048 * 64;
  const unsigned short* Vg = Vg_ + (size_t)bh * 64 * 2048;

  // Q B-frags straight from global: B[n=query c32][k = 8*h32+j], d = dc*16+8*h32+j
  short8 qf[4];
  {
    int rq = wave * 32 + c32;
    #pragma unroll
    for (int dc = 0; dc < 4; ++dc)
      qf[dc] = *(const short8*)(Qg + (size_t)rq * 64 + dc * 16 + h32 * 8);
  }

  floatx16 acc[2];
  acc[0] = (floatx16)0.0f; acc[1] = (floatx16)0.0f;
  float rsp = 0.0f;   // per-lane partial row sum (this lane's key subset)

  for (int s0 = 0; s0 < 2048; s0 += 64) {
    // stage K [64][64] swz8 @0, V^T [64][64] swz8 @8192
    #pragma unroll
    for (int i = 0; i < 2; ++i) {
      int s = (wave * 2 + i) * 64 + lane;
      int r = s >> 3, kc = (s & 7) ^ (r & 7);
      g2l16(Kg + (size_t)(s0 + r) * 64 + kc * 8, smem + (wave * 2 + i) * 1024);
      g2l16(Vg + (size_t)r * 2048 + s0 + kc * 8, smem + 8192 + (wave * 2 + i) * 1024);
    }
    __syncthreads();

    #pragma unroll
    for (int kb = 0; kb < 2; ++kb) {
      // S^T = K * Q^T for 32 keys (kb block)
      floatx16 sc = (floatx16)0.0f;
      #pragma unroll
      for (int dc = 0; dc < 4; ++dc) {
        int rk = kb * 32 + c32;
        int kc = (dc * 2 + h32) ^ (c32 & 7);
        short8 kf = *(const short8*)(smem + (rk * 8 + kc) * 16);
        sc = MFMA32_BF16(kf, qf[dc], sc);
      }
      // p = exp2(s); pack pairs (keys are consecutive within each reg pair)
      float p[16];
      #pragma unroll
      for (int r = 0; r < 16; ++r) { p[r] = fast_exp2(sc[r]); rsp += p[r]; }
      unsigned pk[8];
      #pragma unroll
      for (int i = 0; i < 8; ++i) pk[i] = pack_bf16_rh(p[2 * i], p[2 * i + 1]);
      union { unsigned u[4]; short8 s8; } a0, a1;
      a0.u[0] = pk[0]; a0.u[1] = pk[1]; a0.u[2] = pk[2]; a0.u[3] = pk[3];
      a1.u[0] = pk[4]; a1.u[1] = pk[5]; a1.u[2] = pk[6]; a1.u[3] = pk[7];
      // O += P * V with permuted k-axis (see header comment)
      #pragma unroll
      for (int st = 0; st < 2; ++st) {
        short8 af = st ? a1.s8 : a0.s8;
        int c16a = kb * 4 + 2 * st;        // 16B-chunk of keys base..base+7
        int c16b = c16a + 1;               // keys base+8..base+15
        #pragma unroll
        for (int nb = 0; nb < 2; ++nb) {
          int rv = nb * 32 + c32;
          const char* vrow = smem + 8192 + rv * 128;
          uint2 lo = *(const uint2*)(vrow + ((c16a ^ (rv & 7)) * 16) + h32 * 8);
          uint2 hi = *(const uint2*)(vrow + ((c16b ^ (rv & 7)) * 16) + h32 * 8);
          union { unsigned u[4]; short8 s8; } bv;
          bv.u[0] = lo.x; bv.u[1] = lo.y; bv.u[2] = hi.x; bv.u[3] = hi.y;
          acc[nb] = MFMA32_BF16(af, bv.s8, acc[nb]);
        }
      }
    }
    __syncthreads();
  }

  float lsum = rsp + __shfl_xor(rsp, 32);  // full row sum for query c32

  const int b = bh >> 4, h = bh & 15;
  #pragma unroll
  for (int g = 0; g < 4; ++g) {
    #pragma unroll
    for (int rr = 0; rr < 4; ++rr) {
      int qrel = rr + 8 * g + 4 * h32;          // 32x32 C/D row mapping
      float rl = 1.0f / __shfl(lsum, qrel);     // lane qrel holds row sum of query qrel
      int token = b * 2048 + q0 + wave * 32 + qrel;
      size_t base = (size_t)token * 1024 + h * 64;
      O[base + c32]      = f32_bf16(acc[0][4 * g + rr] * rl);
      O[base + 32 + c32] = f32_bf16(acc[1][4 * g + rr] * rl);
    }
  }
}

// ---------------- output projection GEMM (fp32 out) ----------------

__global__ __launch_bounds__(256, 2)
void gemm_out_k(const unsigned short* __restrict__ A,    // O concat [8192][1024]
                const unsigned short* __restrict__ Bt,   // WOt [1024][1024]
                float* __restrict__ C) {
  __shared__ __align__(16) unsigned short As[8192];
  __shared__ __align__(16) unsigned short Bs[8192];
  const int lane = threadIdx.x & 63;
  const int wave = threadIdx.x >> 6;
  const int quad = lane >> 4;
  const int t = lane & 15;
  const int wm = wave >> 1, wn = wave & 1;
  const int row0 = blockIdx.y * 128;
  const int col0 = blockIdx.x * 128;

  floatx4 acc[4][4];
  #pragma unroll
  for (int i = 0; i < 4; ++i)
    #pragma unroll
    for (int j = 0; j < 4; ++j) acc[i][j] = (floatx4)0.0f;

  for (int k0 = 0; k0 < 1024; k0 += 64) {
    #pragma unroll
    for (int i = 0; i < 4; ++i) {
      int s = (wave * 4 + i) * 64 + lane;
      int r = s >> 3, kc = (s & 7) ^ (r & 7);
      g2l16(A  + (size_t)(row0 + r) * 1024 + k0 + kc * 8, As + (wave * 4 + i) * 512);
      g2l16(Bt + (size_t)(col0 + r) * 1024 + k0 + kc * 8, Bs + (wave * 4 + i) * 512);
    }
    __syncthreads();
    #pragma unroll
    for (int kk = 0; kk < 2; ++kk) {
      short8 af[4], bf[4];
      #pragma unroll
      for (int mt = 0; mt < 4; ++mt) {
        int r = wm * 64 + mt * 16 + t;
        int kc = (kk * 4 + quad) ^ (r & 7);
        af[mt] = *(const short8*)(As + (r * 8 + kc) * 8);
      }
      #pragma unroll
      for (int nt = 0; nt < 4; ++nt) {
        int r = wn * 64 + nt * 16 + t;
        int kc = (kk * 4 + quad) ^ (r & 7);
        bf[nt] = *(const short8*)(Bs + (r * 8 + kc) * 8);
      }
      #pragma unroll
      for (int mt = 0; mt < 4; ++mt)
        #pragma unroll
        for (int nt = 0; nt < 4; ++nt)
          acc[mt][nt] = MFMA_BF16(af[mt], bf[nt], acc[mt][nt]);
    }
    __syncthreads();
  }

  #pragma unroll
  for (int mt = 0; mt < 4; ++mt) {
    int grow0 = row0 + wm * 64 + mt * 16 + quad * 4;
    #pragma unroll
    for (int nt = 0; nt < 4; ++nt) {
      int gcol = col0 + wn * 64 + nt * 16 + t;
      #pragma unroll
      for (int rg = 0; rg < 4; ++rg)
        C[(size_t)(grow0 + rg) * 1024 + gcol] = acc[mt][nt][rg];
    }
  }
}

// ---------------- launcher ----------------

extern "C" void kernel_launch(void* const* d_in, const int* in_sizes, int n_in,
                              void* d_out, int out_size, void* d_ws, size_t ws_size,
                              hipStream_t stream) {
  const float* x  = (const float*)d_in[0];
  const float* WQ = (const float*)d_in[1];
  const float* WK = (const float*)d_in[2];
  const float* WV = (const float*)d_in[3];
  const float* WO = (const float*)d_in[4];
  char* ws = (char*)d_ws;
  // workspace layout (72 MB total):
  unsigned short* xb   = (unsigned short*)(ws);                              // 16MB; reused as O after gemm_qkv
  unsigned short* Wqkv = (unsigned short*)(ws + (size_t)16 * 1024 * 1024);   // 6MB  [3072][1024]
  unsigned short* WOt  = (unsigned short*)(ws + (size_t)22 * 1024 * 1024);   // 2MB  [1024][1024]
  unsigned short* Qb   = (unsigned short*)(ws + (size_t)24 * 1024 * 1024);   // 16MB [64][2048][64]
  unsigned short* Kb   = (unsigned short*)(ws + (size_t)40 * 1024 * 1024);   // 16MB [64][2048][64]
  unsigned short* Vb   = (unsigned short*)(ws + (size_t)56 * 1024 * 1024);   // 16MB [64][64][2048] (V^T)
  float* out = (float*)d_out;

  cvt_x_k<<<8192, 256, 0, stream>>>(x, xb);
  cvt_wqkv_t<<<dim3(16, 48), 256, 0, stream>>>(WQ, WK, WV, Wqkv);
  cvt_wo_t<<<dim3(16, 16), 256, 0, stream>>>(WO, WOt);
  gemm_qkv_k<<<dim3(24, 64), 256, 0, stream>>>(xb, Wqkv, Qb, Kb, Vb);
  attn_k<<<dim3(16, 64), 256, 0, stream>>>(Qb, Kb, Vb, xb /*O reuse*/);
  gemm_out_k<<<dim3(8, 64), 256, 0, stream>>>(xb, WOt, out);
}

// Round 5
// 261.543 us; speedup vs baseline: 1.5710x; 1.0326x over previous
//
#include <hip/hip_runtime.h>
#include <stdint.h>
#include <stddef.h>

// All-bf16 MFMA pipeline for MHSA: cvt -> gemm_qkv -> flash attn -> gemm_out.
// Attention v5: S^T = K*Q^T via 32x32x16 MFMA, fixed-base softmax (scale folded
// into Q). V is stored KEY-PERMUTED (bit2<->bit3 of key index, done free in the
// gemm_qkv epilogue) so each PV step's B-frag is ONE conflict-free b128 read and
// the A-frag is the lane's natural P holdings -- no cross-lane exchange, no b64
// assembly. Row sums via MFMA ones-trick (C-layout matches output loop).

typedef __attribute__((ext_vector_type(8))) short short8;     // bf16x8 frag (4 VGPRs)
typedef __attribute__((ext_vector_type(4))) float floatx4;    // 16x16 C/D frag
typedef __attribute__((ext_vector_type(16))) float floatx16;  // 32x32 C/D frag

#define MFMA_BF16(a, b, c) __builtin_amdgcn_mfma_f32_16x16x32_bf16((a), (b), (c), 0, 0, 0)
#define MFMA32_BF16(a, b, c) __builtin_amdgcn_mfma_f32_32x32x16_bf16((a), (b), (c), 0, 0, 0)

__device__ __forceinline__ unsigned short f32_bf16(float f) {
  union { float f; unsigned u; } v; v.f = f;
  unsigned r = v.u + 0x7fffu + ((v.u >> 16) & 1u);   // RNE
  return (unsigned short)(r >> 16);
}

// pack two floats to bf16x2 (round-half-up): low=a, high=b
__device__ __forceinline__ unsigned pack_bf16_rh(float a, float b) {
  unsigned ua = __float_as_uint(a) + 0x8000u;
  unsigned ub = __float_as_uint(b) + 0x8000u;
  return __builtin_amdgcn_perm(ub, ua, 0x07060302u);
}

__device__ __forceinline__ float fast_exp2(float x) {
#if __has_builtin(__builtin_amdgcn_exp2f)
  return __builtin_amdgcn_exp2f(x);
#else
  return exp2f(x);
#endif
}

__device__ __forceinline__ void g2l16(const void* g, void* l) {
  __builtin_amdgcn_global_load_lds((const __attribute__((address_space(1))) void*)g,
                                   (__attribute__((address_space(3))) void*)l,
                                   16, 0, 0);
}

// ---------------- conversion kernels ----------------

__global__ __launch_bounds__(256) void cvt_x_k(const float* __restrict__ x,
                                               unsigned short* __restrict__ xb) {
  int i = (blockIdx.x * 256 + threadIdx.x) * 4;
  float4 v = *(const float4*)(x + i);
  ushort4 o;
  o.x = f32_bf16(v.x); o.y = f32_bf16(v.y); o.z = f32_bf16(v.z); o.w = f32_bf16(v.w);
  *(ushort4*)(xb + i) = o;
}

// LDS-tiled transpose-convert: Wt[typ*1024 + h*64 + dk][d] = W_typ[h][d][dk].
__global__ __launch_bounds__(256) void cvt_wqkv_t(const float* __restrict__ WQ,
                                                  const float* __restrict__ WK,
                                                  const float* __restrict__ WV,
                                                  unsigned short* __restrict__ Wt) {
  __shared__ unsigned short tile[64][72];
  const int th = blockIdx.y;
  const int typ = th >> 4, h = th & 15;
  const float* W = (typ == 0) ? WQ : ((typ == 1) ? WK : WV);
  const float* src = W + ((size_t)h * 1024 + blockIdx.x * 64) * 64;  // [64 d][64 dk]
  const int tid = threadIdx.x;
  #pragma unroll
  for (int it = 0; it < 16; ++it) {
    int f = it * 256 + tid;
    int dk = f & 63, dl = f >> 6;
    tile[dk][dl] = f32_bf16(src[(size_t)dl * 64 + dk]);
  }
  __syncthreads();
  unsigned short* dst = Wt + (size_t)(typ * 1024 + h * 64) * 1024 + blockIdx.x * 64;
  #pragma unroll
  for (int it = 0; it < 16; ++it) {
    int f = it * 256 + tid;
    int d = f & 63, dk = f >> 6;
    dst[(size_t)dk * 1024 + d] = tile[dk][d];
  }
}

// LDS-tiled transpose-convert: WOt[n][k] = WO[k][n].
__global__ __launch_bounds__(256) void cvt_wo_t(const float* __restrict__ WO,
                                                unsigned short* __restrict__ Wt) {
  __shared__ unsigned short tile[64][72];
  const int nt = blockIdx.x * 64, kt = blockIdx.y * 64;
  const int tid = threadIdx.x;
  #pragma unroll
  for (int it = 0; it < 16; ++it) {
    int f = it * 256 + tid;
    int n = f & 63, kl = f >> 6;
    tile[n][kl] = f32_bf16(WO[(size_t)(kt + kl) * 1024 + nt + n]);
  }
  __syncthreads();
  #pragma unroll
  for (int it = 0; it < 16; ++it) {
    int f = it * 256 + tid;
    int k = f & 63, nl = f >> 6;
    Wt[(size_t)(nt + nl) * 1024 + kt + k] = tile[nl][k];
  }
}

// ---------------- QKV projection GEMM ----------------
// A[8192][1024] bf16, Bt[3072][1024] bf16 (B^T). 128x128 tile, BK=64,
// 4 waves each 64x64 (4x4 16x16x32 MFMA tiles). Epilogue scatters to
// Q (pre-scaled by 0.125*log2e), K [bh][s][dk], V^T [bh][dk][perm(s)] (bf16)
// where perm swaps bits 2<->3 of the key index (for attn's conflict-free PV).

__global__ __launch_bounds__(256, 2)
void gemm_qkv_k(const unsigned short* __restrict__ A,
                const unsigned short* __restrict__ Bt,
                unsigned short* __restrict__ Qo,
                unsigned short* __restrict__ Ko,
                unsigned short* __restrict__ Vo) {
  __shared__ __align__(16) unsigned short As[8192];
  __shared__ __align__(16) unsigned short Bs[8192];
  const int lane = threadIdx.x & 63;
  const int wave = threadIdx.x >> 6;
  const int quad = lane >> 4;
  const int t = lane & 15;
  const int wm = wave >> 1, wn = wave & 1;
  const int row0 = blockIdx.y * 128;
  const int col0 = blockIdx.x * 128;

  floatx4 acc[4][4];
  #pragma unroll
  for (int i = 0; i < 4; ++i)
    #pragma unroll
    for (int j = 0; j < 4; ++j) acc[i][j] = (floatx4)0.0f;

  for (int k0 = 0; k0 < 1024; k0 += 64) {
    #pragma unroll
    for (int i = 0; i < 4; ++i) {
      int s = (wave * 4 + i) * 64 + lane;       // 16B slot index
      int r = s >> 3, kc = (s & 7) ^ (r & 7);   // swizzle8
      g2l16(A  + (size_t)(row0 + r) * 1024 + k0 + kc * 8, As + (wave * 4 + i) * 512);
      g2l16(Bt + (size_t)(col0 + r) * 1024 + k0 + kc * 8, Bs + (wave * 4 + i) * 512);
    }
    __syncthreads();
    #pragma unroll
    for (int kk = 0; kk < 2; ++kk) {
      short8 af[4], bf[4];
      #pragma unroll
      for (int mt = 0; mt < 4; ++mt) {
        int r = wm * 64 + mt * 16 + t;
        int kc = (kk * 4 + quad) ^ (r & 7);
        af[mt] = *(const short8*)(As + (r * 8 + kc) * 8);
      }
      #pragma unroll
      for (int nt = 0; nt < 4; ++nt) {
        int r = wn * 64 + nt * 16 + t;
        int kc = (kk * 4 + quad) ^ (r & 7);
        bf[nt] = *(const short8*)(Bs + (r * 8 + kc) * 8);
      }
      #pragma unroll
      for (int mt = 0; mt < 4; ++mt)
        #pragma unroll
        for (int nt = 0; nt < 4; ++nt)
          acc[mt][nt] = MFMA_BF16(af[mt], bf[nt], acc[mt][nt]);
    }
    __syncthreads();
  }

  const int typ = col0 >> 10;  // block-uniform: 0=Q 1=K 2=V
  const float qscale = 0.18033688011112042f;  // 0.125 * log2(e) folded into Q
  const int qp = ((quad & 1) << 1) | (quad >> 1);  // swap bits: 0,2,1,3
  #pragma unroll
  for (int mt = 0; mt < 4; ++mt) {
    int grow0 = row0 + wm * 64 + mt * 16 + quad * 4;  // token, + rg
    int b = grow0 >> 11;
    int s = grow0 & 2047;
    #pragma unroll
    for (int nt = 0; nt < 4; ++nt) {
      int gcol = col0 + wn * 64 + nt * 16 + t;
      int rem = gcol & 1023;
      int h = rem >> 6, dk = rem & 63;
      int bhh = b * 16 + h;
      if (typ == 0) {
        #pragma unroll
        for (int rg = 0; rg < 4; ++rg)
          Qo[((size_t)bhh * 2048 + s + rg) * 64 + dk] = f32_bf16(acc[mt][nt][rg] * qscale);
      } else if (typ == 1) {
        #pragma unroll
        for (int rg = 0; rg < 4; ++rg)
          Ko[((size_t)bhh * 2048 + s + rg) * 64 + dk] = f32_bf16(acc[mt][nt][rg]);
      } else {
        ushort4 pv;
        pv.x = f32_bf16(acc[mt][nt][0]);
        pv.y = f32_bf16(acc[mt][nt][1]);
        pv.z = f32_bf16(acc[mt][nt][2]);
        pv.w = f32_bf16(acc[mt][nt][3]);
        int sp = (s & ~15) | (qp << 2);           // key-permuted V^T
        *(ushort4*)(Vo + ((size_t)bhh * 64 + dk) * 2048 + sp) = pv;
      }
    }
  }
}

// ---------------- flash attention v5 ----------------
// Block = 128 q rows of one (b,h); 4 waves x 32 rows; 32x32x16 MFMA.
// S^T C-layout: lane (c32,h32) reg r holds P[key kb*32+(r&3)+8*(r>>2)+4*h32][query c32].
// V stored key-permuted (bit2<->bit3) so PV step (kb,st): A-frag = pk[4st..4st+3]
// verbatim, B-frag = one b128 read at chunk kb*4+st*2+h32 (gemm-style swizzle).
// Row sums accumulated by MFMA with B=ones; acc_s C-layout matches output loop.

__global__ __launch_bounds__(256, 4)
void attn_k(const unsigned short* __restrict__ Qg_,  // [bh][2048][64], pre-scaled
            const unsigned short* __restrict__ Kg_,  // [bh][2048][64]
            const unsigned short* __restrict__ Vg_,  // [bh][64][2048] (V^T, key-perm)
            unsigned short* __restrict__ O) {        // [token][h*64+dk]
  __shared__ __align__(16) char smem[16384];         // K@0, V@8192
  const int lane = threadIdx.x & 63;
  const int wave = threadIdx.x >> 6;
  const int h32 = lane >> 5;
  const int c32 = lane & 31;
  const int bh = blockIdx.y;
  const int q0 = blockIdx.x * 128;
  const unsigned short* Qg = Qg_ + ((size_t)bh * 2048 + q0) * 64;
  const unsigned short* Kg = Kg_ + (size_t)bh * 2048 * 64;
  const unsigned short* Vg = Vg_ + (size_t)bh * 64 * 2048;

  // Q B-frags straight from global: B[n=query c32][k = 8*h32+j], d = dc*16+8*h32+j
  short8 qf[4];
  {
    int rq = wave * 32 + c32;
    #pragma unroll
    for (int dc = 0; dc < 4; ++dc)
      qf[dc] = *(const short8*)(Qg + (size_t)rq * 64 + dc * 16 + h32 * 8);
  }

  // ones B-frag for MFMA row sums
  union { unsigned u[4]; short8 s8; } onesf;
  #pragma unroll
  for (int i = 0; i < 4; ++i) onesf.u[i] = 0x3F803F80u;

  floatx16 acc[2], accs;
  acc[0] = (floatx16)0.0f; acc[1] = (floatx16)0.0f; accs = (floatx16)0.0f;

  for (int s0 = 0; s0 < 2048; s0 += 64) {
    // stage K [64][64] swz8 @0, V^T(perm) [64][64] swz8 @8192
    #pragma unroll
    for (int i = 0; i < 2; ++i) {
      int s = (wave * 2 + i) * 64 + lane;
      int r = s >> 3, kc = (s & 7) ^ (r & 7);
      g2l16(Kg + (size_t)(s0 + r) * 64 + kc * 8, smem + (wave * 2 + i) * 1024);
      g2l16(Vg + (size_t)r * 2048 + s0 + kc * 8, smem + 8192 + (wave * 2 + i) * 1024);
    }
    __syncthreads();

    #pragma unroll
    for (int kb = 0; kb < 2; ++kb) {
      // S^T = K * Q^T for 32 keys (kb block)
      floatx16 sc = (floatx16)0.0f;
      #pragma unroll
      for (int dc = 0; dc < 4; ++dc) {
        int rk = kb * 32 + c32;
        int kc = (dc * 2 + h32) ^ (c32 & 7);
        short8 kf = *(const short8*)(smem + (rk * 8 + kc) * 16);
        sc = MFMA32_BF16(kf, qf[dc], sc);
      }
      // p = exp2(s); pack pairs (keys consecutive within each reg pair)
      float p[16];
      #pragma unroll
      for (int r = 0; r < 16; ++r) p[r] = fast_exp2(sc[r]);
      unsigned pk[8];
      #pragma unroll
      for (int i = 0; i < 8; ++i) pk[i] = pack_bf16_rh(p[2 * i], p[2 * i + 1]);
      union { unsigned u[4]; short8 s8; } a0, a1;
      a0.u[0] = pk[0]; a0.u[1] = pk[1]; a0.u[2] = pk[2]; a0.u[3] = pk[3];
      a1.u[0] = pk[4]; a1.u[1] = pk[5]; a1.u[2] = pk[6]; a1.u[3] = pk[7];
      // O += P * V ; rowsum += P * 1  (V key-permuted => single b128 B-frag)
      #pragma unroll
      for (int st = 0; st < 2; ++st) {
        short8 af = st ? a1.s8 : a0.s8;
        int cc = kb * 4 + st * 2 + h32;
        #pragma unroll
        for (int nb = 0; nb < 2; ++nb) {
          int rv = nb * 32 + c32;
          short8 bv = *(const short8*)(smem + 8192 + (rv * 8 + (cc ^ (rv & 7))) * 16);
          acc[nb] = MFMA32_BF16(af, bv, acc[nb]);
        }
        accs = MFMA32_BF16(af, onesf.s8, accs);
      }
    }
    __syncthreads();
  }

  const int b = bh >> 4, h = bh & 15;
  #pragma unroll
  for (int g = 0; g < 4; ++g) {
    #pragma unroll
    for (int rr = 0; rr < 4; ++rr) {
      int qrel = rr + 8 * g + 4 * h32;          // 32x32 C/D row mapping
      float rl = 1.0f / accs[4 * g + rr];       // rowsum of query qrel (all lanes)
      int token = b * 2048 + q0 + wave * 32 + qrel;
      size_t base = (size_t)token * 1024 + h * 64;
      O[base + c32]      = f32_bf16(acc[0][4 * g + rr] * rl);
      O[base + 32 + c32] = f32_bf16(acc[1][4 * g + rr] * rl);
    }
  }
}

// ---------------- output projection GEMM (fp32 out) ----------------

__global__ __launch_bounds__(256, 2)
void gemm_out_k(const unsigned short* __restrict__ A,    // O concat [8192][1024]
                const unsigned short* __restrict__ Bt,   // WOt [1024][1024]
                float* __restrict__ C) {
  __shared__ __align__(16) unsigned short As[8192];
  __shared__ __align__(16) unsigned short Bs[8192];
  const int lane = threadIdx.x & 63;
  const int wave = threadIdx.x >> 6;
  const int quad = lane >> 4;
  const int t = lane & 15;
  const int wm = wave >> 1, wn = wave & 1;
  const int row0 = blockIdx.y * 128;
  const int col0 = blockIdx.x * 128;

  floatx4 acc[4][4];
  #pragma unroll
  for (int i = 0; i < 4; ++i)
    #pragma unroll
    for (int j = 0; j < 4; ++j) acc[i][j] = (floatx4)0.0f;

  for (int k0 = 0; k0 < 1024; k0 += 64) {
    #pragma unroll
    for (int i = 0; i < 4; ++i) {
      int s = (wave * 4 + i) * 64 + lane;
      int r = s >> 3, kc = (s & 7) ^ (r & 7);
      g2l16(A  + (size_t)(row0 + r) * 1024 + k0 + kc * 8, As + (wave * 4 + i) * 512);
      g2l16(Bt + (size_t)(col0 + r) * 1024 + k0 + kc * 8, Bs + (wave * 4 + i) * 512);
    }
    __syncthreads();
    #pragma unroll
    for (int kk = 0; kk < 2; ++kk) {
      short8 af[4], bf[4];
      #pragma unroll
      for (int mt = 0; mt < 4; ++mt) {
        int r = wm * 64 + mt * 16 + t;
        int kc = (kk * 4 + quad) ^ (r & 7);
        af[mt] = *(const short8*)(As + (r * 8 + kc) * 8);
      }
      #pragma unroll
      for (int nt = 0; nt < 4; ++nt) {
        int r = wn * 64 + nt * 16 + t;
        int kc = (kk * 4 + quad) ^ (r & 7);
        bf[nt] = *(const short8*)(Bs + (r * 8 + kc) * 8);
      }
      #pragma unroll
      for (int mt = 0; mt < 4; ++mt)
        #pragma unroll
        for (int nt = 0; nt < 4; ++nt)
          acc[mt][nt] = MFMA_BF16(af[mt], bf[nt], acc[mt][nt]);
    }
    __syncthreads();
  }

  #pragma unroll
  for (int mt = 0; mt < 4; ++mt) {
    int grow0 = row0 + wm * 64 + mt * 16 + quad * 4;
    #pragma unroll
    for (int nt = 0; nt < 4; ++nt) {
      int gcol = col0 + wn * 64 + nt * 16 + t;
      #pragma unroll
      for (int rg = 0; rg < 4; ++rg)
        C[(size_t)(grow0 + rg) * 1024 + gcol] = acc[mt][nt][rg];
    }
  }
}

// ---------------- launcher ----------------

extern "C" void kernel_launch(void* const* d_in, const int* in_sizes, int n_in,
                              void* d_out, int out_size, void* d_ws, size_t ws_size,
                              hipStream_t stream) {
  const float* x  = (const float*)d_in[0];
  const float* WQ = (const float*)d_in[1];
  const float* WK = (const float*)d_in[2];
  const float* WV = (const float*)d_in[3];
  const float* WO = (const float*)d_in[4];
  char* ws = (char*)d_ws;
  // workspace layout (72 MB total):
  unsigned short* xb   = (unsigned short*)(ws);                              // 16MB; reused as O after gemm_qkv
  unsigned short* Wqkv = (unsigned short*)(ws + (size_t)16 * 1024 * 1024);   // 6MB  [3072][1024]
  unsigned short* WOt  = (unsigned short*)(ws + (size_t)22 * 1024 * 1024);   // 2MB  [1024][1024]
  unsigned short* Qb   = (unsigned short*)(ws + (size_t)24 * 1024 * 1024);   // 16MB [64][2048][64]
  unsigned short* Kb   = (unsigned short*)(ws + (size_t)40 * 1024 * 1024);   // 16MB [64][2048][64]
  unsigned short* Vb   = (unsigned short*)(ws + (size_t)56 * 1024 * 1024);   // 16MB [64][64][2048] (V^T key-perm)
  float* out = (float*)d_out;

  cvt_x_k<<<8192, 256, 0, stream>>>(x, xb);
  cvt_wqkv_t<<<dim3(16, 48), 256, 0, stream>>>(WQ, WK, WV, Wqkv);
  cvt_wo_t<<<dim3(16, 16), 256, 0, stream>>>(WO, WOt);
  gemm_qkv_k<<<dim3(24, 64), 256, 0, stream>>>(xb, Wqkv, Qb, Kb, Vb);
  attn_k<<<dim3(16, 64), 256, 0, stream>>>(Qb, Kb, Vb, xb /*O reuse*/);
  gemm_out_k<<<dim3(8, 64), 256, 0, stream>>>(xb, WOt, out);
}

// Round 6
// 250.940 us; speedup vs baseline: 1.6374x; 1.0423x over previous
//
#include <hip/hip_runtime.h>
#include <stdint.h>
#include <stddef.h>

// All-bf16 MFMA pipeline for MHSA: cvt -> gemm_qkv -> flash attn -> gemm_out.
// Attention v6: 64 queries/wave (two 32-q groups SHARE every K/V B-frag read),
// 128-key staging tiles, XCD-affinity grid (bh on blockIdx.x). S^T = K*Q^T via
// 32x32x16 MFMA, fixed-base softmax (scale folded into Q), key-permuted V for
// single-b128 PV B-frags, MFMA ones-trick row sums.

typedef __attribute__((ext_vector_type(8))) short short8;     // bf16x8 frag (4 VGPRs)
typedef __attribute__((ext_vector_type(4))) float floatx4;    // 16x16 C/D frag
typedef __attribute__((ext_vector_type(16))) float floatx16;  // 32x32 C/D frag

#define MFMA_BF16(a, b, c) __builtin_amdgcn_mfma_f32_16x16x32_bf16((a), (b), (c), 0, 0, 0)
#define MFMA32_BF16(a, b, c) __builtin_amdgcn_mfma_f32_32x32x16_bf16((a), (b), (c), 0, 0, 0)

__device__ __forceinline__ unsigned short f32_bf16(float f) {
  union { float f; unsigned u; } v; v.f = f;
  unsigned r = v.u + 0x7fffu + ((v.u >> 16) & 1u);   // RNE
  return (unsigned short)(r >> 16);
}

// pack two floats to bf16x2 (round-half-up): low=a, high=b
__device__ __forceinline__ unsigned pack_bf16_rh(float a, float b) {
  unsigned ua = __float_as_uint(a) + 0x8000u;
  unsigned ub = __float_as_uint(b) + 0x8000u;
  return __builtin_amdgcn_perm(ub, ua, 0x07060302u);
}

__device__ __forceinline__ float fast_exp2(float x) {
#if __has_builtin(__builtin_amdgcn_exp2f)
  return __builtin_amdgcn_exp2f(x);
#else
  return exp2f(x);
#endif
}

__device__ __forceinline__ void g2l16(const void* g, void* l) {
  __builtin_amdgcn_global_load_lds((const __attribute__((address_space(1))) void*)g,
                                   (__attribute__((address_space(3))) void*)l,
                                   16, 0, 0);
}

// ---------------- conversion kernels ----------------

__global__ __launch_bounds__(256) void cvt_x_k(const float* __restrict__ x,
                                               unsigned short* __restrict__ xb) {
  int i = (blockIdx.x * 256 + threadIdx.x) * 4;
  float4 v = *(const float4*)(x + i);
  ushort4 o;
  o.x = f32_bf16(v.x); o.y = f32_bf16(v.y); o.z = f32_bf16(v.z); o.w = f32_bf16(v.w);
  *(ushort4*)(xb + i) = o;
}

// Merged LDS-tiled transpose-converts:
//  bid <  768: Wqkv[typ*1024 + h*64 + dk][d] = W_typ[h][d][dk]
//  bid >= 768: WOt[n][k] = WO[k][n]
__global__ __launch_bounds__(256) void cvt_w_k(const float* __restrict__ WQ,
                                               const float* __restrict__ WK,
                                               const float* __restrict__ WV,
                                               const float* __restrict__ WO,
                                               unsigned short* __restrict__ Wqkv,
                                               unsigned short* __restrict__ WOt) {
  __shared__ unsigned short tile[64][72];
  const int bid = blockIdx.x;
  const int tid = threadIdx.x;
  if (bid < 768) {
    const int th = bid >> 4;
    const int typ = th >> 4, h = th & 15;
    const float* W = (typ == 0) ? WQ : ((typ == 1) ? WK : WV);
    const float* src = W + ((size_t)h * 1024 + (bid & 15) * 64) * 64;  // [64 d][64 dk]
    #pragma unroll
    for (int it = 0; it < 16; ++it) {
      int f = it * 256 + tid;
      int dk = f & 63, dl = f >> 6;
      tile[dk][dl] = f32_bf16(src[(size_t)dl * 64 + dk]);
    }
    __syncthreads();
    unsigned short* dst = Wqkv + (size_t)(typ * 1024 + h * 64) * 1024 + (bid & 15) * 64;
    #pragma unroll
    for (int it = 0; it < 16; ++it) {
      int f = it * 256 + tid;
      int d = f & 63, dk = f >> 6;
      dst[(size_t)dk * 1024 + d] = tile[dk][d];
    }
  } else {
    const int id2 = bid - 768;
    const int nt = (id2 & 15) * 64, kt = (id2 >> 4) * 64;
    #pragma unroll
    for (int it = 0; it < 16; ++it) {
      int f = it * 256 + tid;
      int n = f & 63, kl = f >> 6;
      tile[n][kl] = f32_bf16(WO[(size_t)(kt + kl) * 1024 + nt + n]);
    }
    __syncthreads();
    #pragma unroll
    for (int it = 0; it < 16; ++it) {
      int f = it * 256 + tid;
      int k = f & 63, nl = f >> 6;
      WOt[(size_t)(nt + nl) * 1024 + kt + k] = tile[nl][k];
    }
  }
}

// ---------------- QKV projection GEMM ----------------
// A[8192][1024] bf16, Bt[3072][1024] bf16 (B^T). 128x128 tile, BK=64,
// 4 waves each 64x64 (4x4 16x16x32 MFMA tiles). Epilogue scatters to
// Q (pre-scaled by 0.125*log2e), K [bh][s][dk], V^T [bh][dk][perm(s)] (bf16)
// where perm swaps bits 2<->3 of the key index (for attn's conflict-free PV).

__global__ __launch_bounds__(256, 2)
void gemm_qkv_k(const unsigned short* __restrict__ A,
                const unsigned short* __restrict__ Bt,
                unsigned short* __restrict__ Qo,
                unsigned short* __restrict__ Ko,
                unsigned short* __restrict__ Vo) {
  __shared__ __align__(16) unsigned short As[8192];
  __shared__ __align__(16) unsigned short Bs[8192];
  const int lane = threadIdx.x & 63;
  const int wave = threadIdx.x >> 6;
  const int quad = lane >> 4;
  const int t = lane & 15;
  const int wm = wave >> 1, wn = wave & 1;
  const int row0 = blockIdx.y * 128;
  const int col0 = blockIdx.x * 128;

  floatx4 acc[4][4];
  #pragma unroll
  for (int i = 0; i < 4; ++i)
    #pragma unroll
    for (int j = 0; j < 4; ++j) acc[i][j] = (floatx4)0.0f;

  for (int k0 = 0; k0 < 1024; k0 += 64) {
    #pragma unroll
    for (int i = 0; i < 4; ++i) {
      int s = (wave * 4 + i) * 64 + lane;       // 16B slot index
      int r = s >> 3, kc = (s & 7) ^ (r & 7);   // swizzle8
      g2l16(A  + (size_t)(row0 + r) * 1024 + k0 + kc * 8, As + (wave * 4 + i) * 512);
      g2l16(Bt + (size_t)(col0 + r) * 1024 + k0 + kc * 8, Bs + (wave * 4 + i) * 512);
    }
    __syncthreads();
    #pragma unroll
    for (int kk = 0; kk < 2; ++kk) {
      short8 af[4], bf[4];
      #pragma unroll
      for (int mt = 0; mt < 4; ++mt) {
        int r = wm * 64 + mt * 16 + t;
        int kc = (kk * 4 + quad) ^ (r & 7);
        af[mt] = *(const short8*)(As + (r * 8 + kc) * 8);
      }
      #pragma unroll
      for (int nt = 0; nt < 4; ++nt) {
        int r = wn * 64 + nt * 16 + t;
        int kc = (kk * 4 + quad) ^ (r & 7);
        bf[nt] = *(const short8*)(Bs + (r * 8 + kc) * 8);
      }
      #pragma unroll
      for (int mt = 0; mt < 4; ++mt)
        #pragma unroll
        for (int nt = 0; nt < 4; ++nt)
          acc[mt][nt] = MFMA_BF16(af[mt], bf[nt], acc[mt][nt]);
    }
    __syncthreads();
  }

  const int typ = col0 >> 10;  // block-uniform: 0=Q 1=K 2=V
  const float qscale = 0.18033688011112042f;  // 0.125 * log2(e) folded into Q
  const int qp = ((quad & 1) << 1) | (quad >> 1);  // swap bits: 0,2,1,3
  #pragma unroll
  for (int mt = 0; mt < 4; ++mt) {
    int grow0 = row0 + wm * 64 + mt * 16 + quad * 4;  // token, + rg
    int b = grow0 >> 11;
    int s = grow0 & 2047;
    #pragma unroll
    for (int nt = 0; nt < 4; ++nt) {
      int gcol = col0 + wn * 64 + nt * 16 + t;
      int rem = gcol & 1023;
      int h = rem >> 6, dk = rem & 63;
      int bhh = b * 16 + h;
      if (typ == 0) {
        #pragma unroll
        for (int rg = 0; rg < 4; ++rg)
          Qo[((size_t)bhh * 2048 + s + rg) * 64 + dk] = f32_bf16(acc[mt][nt][rg] * qscale);
      } else if (typ == 1) {
        #pragma unroll
        for (int rg = 0; rg < 4; ++rg)
          Ko[((size_t)bhh * 2048 + s + rg) * 64 + dk] = f32_bf16(acc[mt][nt][rg]);
      } else {
        ushort4 pv;
        pv.x = f32_bf16(acc[mt][nt][0]);
        pv.y = f32_bf16(acc[mt][nt][1]);
        pv.z = f32_bf16(acc[mt][nt][2]);
        pv.w = f32_bf16(acc[mt][nt][3]);
        int sp = (s & ~15) | (qp << 2);           // key-permuted V^T
        *(ushort4*)(Vo + ((size_t)bhh * 64 + dk) * 2048 + sp) = pv;
      }
    }
  }
}

// ---------------- flash attention v6 ----------------
// Block = 256 q rows of one (b,h); 4 waves x 64 q (two 32-q groups sharing all
// K/V B-frag reads). 128-key staging tiles (K 16KB + V 16KB = 32KB LDS).
// S^T C-layout: lane (c32,h32) reg r holds P[key kb*32+(r&3)+8*(r>>2)+4*h32][query c32].
// V key-permuted (bit2<->bit3) -> PV step (kb,st): A-frag = pk[4st..4st+3],
// B-frag = one b128 at granule col kb*4+st*2+h32. Row sums via MFMA ones.
// Grid (bh=64, qtile=8): flat id % 8 == bh % 8 -> per-head XCD L2 affinity.

__global__ __launch_bounds__(256, 2)
void attn_k(const unsigned short* __restrict__ Qg_,  // [bh][2048][64], pre-scaled
            const unsigned short* __restrict__ Kg_,  // [bh][2048][64]
            const unsigned short* __restrict__ Vg_,  // [bh][64][2048] (V^T, key-perm)
            unsigned short* __restrict__ O) {        // [token][h*64+dk]
  __shared__ __align__(16) char smem[32768];         // K@0 [128k][64d], V@16384 [64d][128k]
  const int lane = threadIdx.x & 63;
  const int wave = threadIdx.x >> 6;
  const int h32 = lane >> 5;
  const int c32 = lane & 31;
  const int bh = blockIdx.x;
  const int q0 = blockIdx.y * 256;
  const unsigned short* Qg = Qg_ + ((size_t)bh * 2048 + q0) * 64;
  const unsigned short* Kg = Kg_ + (size_t)bh * 2048 * 64;
  const unsigned short* Vg = Vg_ + (size_t)bh * 64 * 2048;

  // Q B-frags straight from global for both query groups:
  // group g covers queries wave*64 + g*32 + c32; B[n=query][k=8*h32+j]
  short8 qf[2][4];
  #pragma unroll
  for (int g = 0; g < 2; ++g) {
    int rq = wave * 64 + g * 32 + c32;
    #pragma unroll
    for (int dc = 0; dc < 4; ++dc)
      qf[g][dc] = *(const short8*)(Qg + (size_t)rq * 64 + dc * 16 + h32 * 8);
  }

  // ones B-frag for MFMA row sums
  union { unsigned u[4]; short8 s8; } onesf;
  #pragma unroll
  for (int i = 0; i < 4; ++i) onesf.u[i] = 0x3F803F80u;

  floatx16 acc[2][2], accs[2];
  #pragma unroll
  for (int g = 0; g < 2; ++g) {
    acc[g][0] = (floatx16)0.0f; acc[g][1] = (floatx16)0.0f; accs[g] = (floatx16)0.0f;
  }

  for (int s0 = 0; s0 < 2048; s0 += 128) {
    // stage K [128 keys][64 d] swz8 @0 ; V^T(perm) [64 d][128 keys] swz (16 gran/row) @16384
    #pragma unroll
    for (int i = 0; i < 4; ++i) {
      int s = (wave * 4 + i) * 64 + lane;          // granule slot 0..1023
      int rk = s >> 3, ck = (s & 7) ^ (rk & 7);    // K: 8 granules/row
      g2l16(Kg + (size_t)(s0 + rk) * 64 + ck * 8, smem + s * 16);
      int rv = s >> 4, cv = (s & 15) ^ (rv & 7);   // V: 16 granules/row
      g2l16(Vg + (size_t)rv * 2048 + s0 + cv * 8, smem + 16384 + s * 16);
    }
    __syncthreads();

    #pragma unroll
    for (int kb = 0; kb < 4; ++kb) {
      // S^T = K * Q^T for 32 keys (kb block), both query groups share kf
      floatx16 sc0 = (floatx16)0.0f, sc1 = (floatx16)0.0f;
      #pragma unroll
      for (int dc = 0; dc < 4; ++dc) {
        int rk = kb * 32 + c32;
        int kc = (dc * 2 + h32) ^ (rk & 7);
        short8 kf = *(const short8*)(smem + (rk * 8 + kc) * 16);
        sc0 = MFMA32_BF16(kf, qf[0][dc], sc0);
        sc1 = MFMA32_BF16(kf, qf[1][dc], sc1);
      }
      // softmax + pack for both groups
      unsigned pk0[8], pk1[8];
      #pragma unroll
      for (int i = 0; i < 8; ++i) {
        float a0 = fast_exp2(sc0[2 * i]), b0 = fast_exp2(sc0[2 * i + 1]);
        float a1 = fast_exp2(sc1[2 * i]), b1 = fast_exp2(sc1[2 * i + 1]);
        pk0[i] = pack_bf16_rh(a0, b0);
        pk1[i] = pack_bf16_rh(a1, b1);
      }
      // O += P*V ; rowsum += P*1  (V key-permuted => single b128 B-frag, shared)
      #pragma unroll
      for (int st = 0; st < 2; ++st) {
        union { unsigned u[4]; short8 s8; } af0, af1;
        #pragma unroll
        for (int i = 0; i < 4; ++i) { af0.u[i] = pk0[4 * st + i]; af1.u[i] = pk1[4 * st + i]; }
        int cc = kb * 4 + st * 2 + h32;
        #pragma unroll
        for (int nb = 0; nb < 2; ++nb) {
          int rv = nb * 32 + c32;
          short8 bv = *(const short8*)(smem + 16384 + (rv * 16 + (cc ^ (rv & 7))) * 16);
          acc[0][nb] = MFMA32_BF16(af0.s8, bv, acc[0][nb]);
          acc[1][nb] = MFMA32_BF16(af1.s8, bv, acc[1][nb]);
        }
        accs[0] = MFMA32_BF16(af0.s8, onesf.s8, accs[0]);
        accs[1] = MFMA32_BF16(af1.s8, onesf.s8, accs[1]);
      }
    }
    __syncthreads();
  }

  const int b = bh >> 4, h = bh & 15;
  #pragma unroll
  for (int g = 0; g < 2; ++g) {
    #pragma unroll
    for (int gg = 0; gg < 4; ++gg) {
      #pragma unroll
      for (int rr = 0; rr < 4; ++rr) {
        int qrel = rr + 8 * gg + 4 * h32;            // 32x32 C/D row mapping
        float rl = 1.0f / accs[g][4 * gg + rr];      // rowsum of this query
        int token = b * 2048 + q0 + wave * 64 + g * 32 + qrel;
        size_t base = (size_t)token * 1024 + h * 64;
        O[base + c32]      = f32_bf16(acc[g][0][4 * gg + rr] * rl);
        O[base + 32 + c32] = f32_bf16(acc[g][1][4 * gg + rr] * rl);
      }
    }
  }
}

// ---------------- output projection GEMM (fp32 out) ----------------

__global__ __launch_bounds__(256, 2)
void gemm_out_k(const unsigned short* __restrict__ A,    // O concat [8192][1024]
                const unsigned short* __restrict__ Bt,   // WOt [1024][1024]
                float* __restrict__ C) {
  __shared__ __align__(16) unsigned short As[8192];
  __shared__ __align__(16) unsigned short Bs[8192];
  const int lane = threadIdx.x & 63;
  const int wave = threadIdx.x >> 6;
  const int quad = lane >> 4;
  const int t = lane & 15;
  const int wm = wave >> 1, wn = wave & 1;
  const int row0 = blockIdx.y * 128;
  const int col0 = blockIdx.x * 128;

  floatx4 acc[4][4];
  #pragma unroll
  for (int i = 0; i < 4; ++i)
    #pragma unroll
    for (int j = 0; j < 4; ++j) acc[i][j] = (floatx4)0.0f;

  for (int k0 = 0; k0 < 1024; k0 += 64) {
    #pragma unroll
    for (int i = 0; i < 4; ++i) {
      int s = (wave * 4 + i) * 64 + lane;
      int r = s >> 3, kc = (s & 7) ^ (r & 7);
      g2l16(A  + (size_t)(row0 + r) * 1024 + k0 + kc * 8, As + (wave * 4 + i) * 512);
      g2l16(Bt + (size_t)(col0 + r) * 1024 + k0 + kc * 8, Bs + (wave * 4 + i) * 512);
    }
    __syncthreads();
    #pragma unroll
    for (int kk = 0; kk < 2; ++kk) {
      short8 af[4], bf[4];
      #pragma unroll
      for (int mt = 0; mt < 4; ++mt) {
        int r = wm * 64 + mt * 16 + t;
        int kc = (kk * 4 + quad) ^ (r & 7);
        af[mt] = *(const short8*)(As + (r * 8 + kc) * 8);
      }
      #pragma unroll
      for (int nt = 0; nt < 4; ++nt) {
        int r = wn * 64 + nt * 16 + t;
        int kc = (kk * 4 + quad) ^ (r & 7);
        bf[nt] = *(const short8*)(Bs + (r * 8 + kc) * 8);
      }
      #pragma unroll
      for (int mt = 0; mt < 4; ++mt)
        #pragma unroll
        for (int nt = 0; nt < 4; ++nt)
          acc[mt][nt] = MFMA_BF16(af[mt], bf[nt], acc[mt][nt]);
    }
    __syncthreads();
  }

  #pragma unroll
  for (int mt = 0; mt < 4; ++mt) {
    int grow0 = row0 + wm * 64 + mt * 16 + quad * 4;
    #pragma unroll
    for (int nt = 0; nt < 4; ++nt) {
      int gcol = col0 + wn * 64 + nt * 16 + t;
      #pragma unroll
      for (int rg = 0; rg < 4; ++rg)
        C[(size_t)(grow0 + rg) * 1024 + gcol] = acc[mt][nt][rg];
    }
  }
}

// ---------------- launcher ----------------

extern "C" void kernel_launch(void* const* d_in, const int* in_sizes, int n_in,
                              void* d_out, int out_size, void* d_ws, size_t ws_size,
                              hipStream_t stream) {
  const float* x  = (const float*)d_in[0];
  const float* WQ = (const float*)d_in[1];
  const float* WK = (const float*)d_in[2];
  const float* WV = (const float*)d_in[3];
  const float* WO = (const float*)d_in[4];
  char* ws = (char*)d_ws;
  // workspace layout (72 MB total):
  unsigned short* xb   = (unsigned short*)(ws);                              // 16MB; reused as O after gemm_qkv
  unsigned short* Wqkv = (unsigned short*)(ws + (size_t)16 * 1024 * 1024);   // 6MB  [3072][1024]
  unsigned short* WOt  = (unsigned short*)(ws + (size_t)22 * 1024 * 1024);   // 2MB  [1024][1024]
  unsigned short* Qb   = (unsigned short*)(ws + (size_t)24 * 1024 * 1024);   // 16MB [64][2048][64]
  unsigned short* Kb   = (unsigned short*)(ws + (size_t)40 * 1024 * 1024);   // 16MB [64][2048][64]
  unsigned short* Vb   = (unsigned short*)(ws + (size_t)56 * 1024 * 1024);   // 16MB [64][64][2048] (V^T key-perm)
  float* out = (float*)d_out;

  cvt_x_k<<<8192, 256, 0, stream>>>(x, xb);
  cvt_w_k<<<1024, 256, 0, stream>>>(WQ, WK, WV, WO, Wqkv, WOt);
  gemm_qkv_k<<<dim3(24, 64), 256, 0, stream>>>(xb, Wqkv, Qb, Kb, Vb);
  attn_k<<<dim3(64, 8), 256, 0, stream>>>(Qb, Kb, Vb, xb /*O reuse*/);
  gemm_out_k<<<dim3(8, 64), 256, 0, stream>>>(xb, WOt, out);
}